// Round 3
// baseline (195.045 us; speedup 1.0000x reference)
//
#include <hip/hip_runtime.h>
#include <cfloat>

#define B_   16
#define C_   256
#define K_   1024
#define HW_  4096
#define N_   (B_ * HW_)          // 65536 rows
#define CHW_ (C_ * HW_)          // 1048576

// d_out layout (floats): zq [0, 16777216), seq [16777216, 16842752), losses [16842752, 16842754)
#define SEQ_OFF  (B_ * C_ * HW_)     // 16777216
#define LOSS_OFF (SEQ_OFF + N_)      // 16842752
// staging inside the zq region (all overwritten by gather at the end):
//   w_t    f32 [C][K]                 @ float 0        (262144)
//   wnorm  f32 [K]                    @ float 262144   (1024)
//   whb_f  bf16 frag-ordered [32][16KB] @ float 263168 (131072 floats worth)
//   wlb_f  bf16 frag-ordered          @ float 394240   (131072)
//   rlist  int [N]                    @ float 525312
//   rcount int                        @ float 590848

#define WT_F    0
#define WN_F    262144
#define WHB_F   263168
#define WLB_F   394240
#define RLIST_F 525312
#define RCNT_F  590848

#define EPS_GAP 0.03125f

typedef short bf16x8 __attribute__((ext_vector_type(8)));
typedef float f32x16 __attribute__((ext_vector_type(16)));

__device__ __forceinline__ unsigned short bf16_rne(float f) {
    unsigned u = __float_as_uint(f);
    unsigned r = u + 0x7fffu + ((u >> 16) & 1u);
    return (unsigned short)(r >> 16);
}
__device__ __forceinline__ float bf16_to_f(unsigned short h) {
    return __uint_as_float(((unsigned)h) << 16);
}

// ---------------- prep 1: transpose weight [K][C] -> w_t [C][K] (f32, for rescue) ----------------
__global__ __launch_bounds__(256) void transpose_w_kernel(
    const float* __restrict__ w, float* __restrict__ w_t)
{
    const int tid = blockIdx.x * 256 + threadIdx.x;   // 0 .. 65535
    const float4 v = reinterpret_cast<const float4*>(w)[tid];
    const int k = tid >> 6;
    const int c = (tid & 63) * 4;
    w_t[(size_t)(c + 0) * K_ + k] = v.x;
    w_t[(size_t)(c + 1) * K_ + k] = v.y;
    w_t[(size_t)(c + 2) * K_ + k] = v.z;
    w_t[(size_t)(c + 3) * K_ + k] = v.w;
}

// ---------------- prep 2: wnorm[k] = ||w_k||^2 (f32 exact) ----------------
__global__ __launch_bounds__(256) void wnorm_kernel(
    const float* __restrict__ w, float* __restrict__ wn)
{
    const int k = blockIdx.x * 256 + threadIdx.x;
    const float4* wr = reinterpret_cast<const float4*>(w + (size_t)k * C_);
    float s = 0.f;
#pragma unroll 8
    for (int c4 = 0; c4 < C_ / 4; ++c4) {
        const float4 v = wr[c4];
        s += v.x * v.x + v.y * v.y + v.z * v.z + v.w * v.w;
    }
    wn[k] = s;
}

// ---------------- prep 3: split w into bf16 hi/lo in MFMA B-fragment order ----------------
// Chunk ch (32 codes) occupies 16KB (8192 bf16). Element (code k = ch*32+col,
// channel c = c8*8 + j) lands at elem = ch*8192 + c8*256 + col*8 + j, so a
// 32x32x16 B-fragment ds_read for (ks, khalf=l>>5, col=l&31) is LDS base + l*16.
__global__ __launch_bounds__(256) void wsplit_frag_kernel(
    const float* __restrict__ w, unsigned short* __restrict__ whb,
    unsigned short* __restrict__ wlb)
{
    const int tid = blockIdx.x * 256 + threadIdx.x;   // 0..32767
    const int k  = tid >> 5;
    const int c8 = tid & 31;
    const float* src = w + (size_t)k * C_ + c8 * 8;
    unsigned short h[8], lo[8];
#pragma unroll
    for (int j = 0; j < 8; ++j) {
        const float v = src[j];
        h[j] = bf16_rne(v);
        lo[j] = bf16_rne(v - bf16_to_f(h[j]));
    }
    const size_t dst = (size_t)(k >> 5) * 8192 + (size_t)c8 * 256 + (size_t)(k & 31) * 8;
#pragma unroll
    for (int j = 0; j < 8; ++j) { whb[dst + j] = h[j]; wlb[dst + j] = lo[j]; }
}

// ---------------- pass A: 32x32x16 MFMA approximate argmin with gap flagging ----------------
// 512 blocks x 256 threads (4 waves). Block: 128 rows (one b, hw0..hw0+127).
// Wave wv owns rows wv*32..wv*32+31. x hi/lo A-fragments in registers (128 VGPR).
// w hi/lo streamed per 32-code chunk via linear global_load_lds (frag-ordered
// global layout -> conflict-free lane-contiguous ds_read_b128).
__global__ __launch_bounds__(256, 2) void argmin_mfma_kernel(
    const float* __restrict__ x, const unsigned short* __restrict__ whb,
    const unsigned short* __restrict__ wlb, const float* __restrict__ wnorm,
    float* __restrict__ seq, int* __restrict__ rlist, int* __restrict__ rcount)
{
    __shared__ __align__(16) char lds[65536];   // 2 x 32KB chunk buffers; x-staging aliases buf0
    const int t  = threadIdx.x;
    const int l  = t & 63;
    const int wv = t >> 6;
    const int nb = blockIdx.x;
    const int b  = nb >> 5;
    const int hw0 = (nb & 31) << 7;
    const float* xb = x + (size_t)b * CHW_ + hw0;

    const int col   = l & 31;   // A row / B col / D col lane index
    const int khalf = l >> 5;   // k-half within 16

    // ---- x setup: stage f32 slab (32 ch x 128 rows), extract A-frags, split bf16 hi/lo ----
    bf16x8 ah[16], al[16];
    {
        float* xs = (float*)lds;                      // [32][132] f32 (16.9 KB)
#pragma unroll
        for (int cc = 0; cc < 8; ++cc) {
#pragma unroll
            for (int q = 0; q < 4; ++q) {
                const int fi = q * 256 + t;           // 0..1023 float4 slots
                const int cl = fi >> 5;               // 0..31
                const int r4 = (fi & 31) << 2;        // 0..124
                const float4 v = *reinterpret_cast<const float4*>(
                    xb + (size_t)(cc * 32 + cl) * HW_ + r4);
                *reinterpret_cast<float4*>(xs + cl * 132 + r4) = v;
            }
            __syncthreads();
            const int row = wv * 32 + col;
#pragma unroll
            for (int h = 0; h < 2; ++h) {
                const int ks = cc * 2 + h;
                bf16x8 vh, vl;
#pragma unroll
                for (int j = 0; j < 8; ++j) {
                    const float v = xs[(h * 16 + khalf * 8 + j) * 132 + row];
                    const unsigned short hi = bf16_rne(v);
                    vh[j] = (short)hi;
                    vl[j] = (short)bf16_rne(v - bf16_to_f(hi));
                }
                ah[ks] = vh;
                al[ks] = vl;
            }
            __syncthreads();
        }
    }

    char* const buf0 = lds;
    char* const buf1 = lds + 32768;
    const char* whbB = (const char*)whb;
    const char* wlbB = (const char*)wlb;

    // stage chunk ch into dst: [hi 16K | lo 16K], linear (uniform base + lane*16)
#define STAGE_CHUNK(ch, dst)                                                        \
    {                                                                               \
        const size_t goff = (size_t)(ch) * 16384 + (size_t)(wv * 4) * 1024;         \
        const int    loff = wv * 4 * 1024;                                          \
        _Pragma("unroll")                                                           \
        for (int rr = 0; rr < 4; ++rr) {                                            \
            __builtin_amdgcn_global_load_lds(                                       \
                (const __attribute__((address_space(1))) void*)                    \
                    (whbB + goff + rr * 1024 + l * 16),                             \
                (__attribute__((address_space(3))) void*)                           \
                    ((dst) + loff + rr * 1024), 16, 0, 0);                          \
            __builtin_amdgcn_global_load_lds(                                       \
                (const __attribute__((address_space(1))) void*)                    \
                    (wlbB + goff + rr * 1024 + l * 16),                             \
                (__attribute__((address_space(3))) void*)                           \
                    ((dst) + 16384 + loff + rr * 1024), 16, 0, 0);                  \
        }                                                                           \
    }

    STAGE_CHUNK(0, buf0);
    __syncthreads();

    float m1v[16], m2v[16];
    int   i1v[16];
#pragma unroll
    for (int r = 0; r < 16; ++r) { m1v[r] = FLT_MAX; m2v[r] = FLT_MAX; i1v[r] = 0; }

    for (int ch = 0; ch < 32; ++ch) {
        char* const curbuf = (ch & 1) ? buf1 : buf0;
        if (ch < 31) { STAGE_CHUNK(ch + 1, (ch & 1) ? buf0 : buf1); }
        const int k0 = ch * 32;
        const float wnc = wnorm[k0 + col];

        f32x16 accA = {0.f}, accB = {0.f};
#pragma unroll
        for (int r = 0; r < 16; ++r) { accA[r] = 0.f; accB[r] = 0.f; }

        const char* hb = curbuf;
        const char* lb = curbuf + 16384;
#pragma unroll
        for (int ks = 0; ks < 16; ++ks) {
            const bf16x8 bh = *reinterpret_cast<const bf16x8*>(hb + ks * 1024 + (l << 4));
            const bf16x8 bl = *reinterpret_cast<const bf16x8*>(lb + ks * 1024 + (l << 4));
            accA = __builtin_amdgcn_mfma_f32_32x32x16_bf16(ah[ks], bh, accA, 0, 0, 0);
            accB = __builtin_amdgcn_mfma_f32_32x32x16_bf16(al[ks], bh, accB, 0, 0, 0);
            accA = __builtin_amdgcn_mfma_f32_32x32x16_bf16(ah[ks], bl, accA, 0, 0, 0);
        }

        // epilogue: 16 rows per lane, single code k0+col
        const int kidx = k0 + col;
#pragma unroll
        for (int r = 0; r < 16; ++r) {
            const float d = fmaf(-2.f, accA[r] + accB[r], wnc);
            const bool lt = d < m1v[r];
            m2v[r] = lt ? m1v[r] : fminf(m2v[r], d);
            i1v[r] = lt ? kidx : i1v[r];
            m1v[r] = lt ? d : m1v[r];
        }
        __syncthreads();
    }
#undef STAGE_CHUNK

    // merge across the 32 code-lanes (lane bits 0..4; halves stay separate)
#pragma unroll
    for (int mask = 1; mask <= 16; mask <<= 1) {
#pragma unroll
        for (int r = 0; r < 16; ++r) {
            const float om1 = __shfl_xor(m1v[r], mask, 64);
            const int   oi1 = __shfl_xor(i1v[r], mask, 64);
            const float om2 = __shfl_xor(m2v[r], mask, 64);
            const bool lt = om1 < m1v[r] || (om1 == m1v[r] && oi1 < i1v[r]);
            const float nm2 = lt ? fminf(m1v[r], om2) : fminf(m2v[r], om1);
            i1v[r] = lt ? oi1 : i1v[r];
            m1v[r] = lt ? om1 : m1v[r];
            m2v[r] = nm2;
        }
    }

    if (col == 0) {
#pragma unroll
        for (int r = 0; r < 16; ++r) {
            const int row_local = (r & 3) + 8 * (r >> 2) + 4 * khalf;   // 0..31
            const int n = b * HW_ + hw0 + wv * 32 + row_local;
            seq[n] = (float)i1v[r];
            if (m2v[r] - m1v[r] < EPS_GAP) {
                const int pos = atomicAdd(rcount, 1);
                rlist[pos] = n;
            }
        }
    }
}

// ---------------- rescue: exact f32 re-argmin for flagged rows ----------------
__global__ __launch_bounds__(256) void rescue_kernel(
    const float* __restrict__ x, const float* __restrict__ w_t,
    const float* __restrict__ wnorm, const int* __restrict__ rlist,
    const int* __restrict__ rcount, float* __restrict__ seq)
{
    __shared__ float xr[C_];
    __shared__ float bvs[4];
    __shared__ int   bis[4];
    const int t = threadIdx.x;
    const int cnt = *rcount;
    for (int ii = blockIdx.x; ii < cnt; ii += gridDim.x) {
        const int n = rlist[ii];
        const int b = n >> 12, hw = n & 4095;
        xr[t] = x[(size_t)b * CHW_ + (size_t)t * HW_ + hw];
        __syncthreads();
        float best = FLT_MAX; int bidx = 0;
#pragma unroll
        for (int q = 0; q < 4; ++q) {
            const int k = t + q * 256;
            float acc = 0.f;
            for (int c = 0; c < C_; ++c) acc = fmaf(xr[c], w_t[(size_t)c * K_ + k], acc);
            const float d = wnorm[k] - 2.f * acc;
            if (d < best || (d == best && k < bidx)) { best = d; bidx = k; }
        }
#pragma unroll
        for (int mask = 1; mask < 64; mask <<= 1) {
            const float ov = __shfl_xor(best, mask, 64);
            const int   oi = __shfl_xor(bidx, mask, 64);
            if (ov < best || (ov == best && oi < bidx)) { best = ov; bidx = oi; }
        }
        if ((t & 63) == 0) { bvs[t >> 6] = best; bis[t >> 6] = bidx; }
        __syncthreads();
        if (t == 0) {
            float bv = bvs[0]; int bi = bis[0];
#pragma unroll
            for (int w2 = 1; w2 < 4; ++w2)
                if (bvs[w2] < bv || (bvs[w2] == bv && bis[w2] < bi)) { bv = bvs[w2]; bi = bis[w2]; }
            seq[n] = (float)bi;
        }
        __syncthreads();
    }
}

// ---------------- gather z, write zq, accumulate loss ----------------
__global__ __launch_bounds__(256) void gather_kernel(
    const float* __restrict__ x, const float* __restrict__ w,
    const float* __restrict__ seqf, float* __restrict__ zq,
    double* __restrict__ loss_acc)
{
    const int t   = threadIdx.x;
    const int nb  = blockIdx.x;
    const int b   = nb >> 6;
    const int hw0 = (nb & 63) << 6;
    const int r   = t & 63;
    const int cg  = t >> 6;
    const float* xb = x  + (size_t)b * CHW_ + hw0;
    float*       zb = zq + (size_t)b * CHW_ + hw0;
    const int idx = (int)seqf[b * HW_ + hw0 + r];
    const float* wrow = w + (size_t)idx * C_;

    float lsum = 0.f;
#pragma unroll 4
    for (int cc = 0; cc < 64; ++cc) {
        const int c = cg * 64 + cc;
        const float xv = xb[(size_t)c * HW_ + r];
        const float d  = wrow[c] - xv;
        zb[(size_t)c * HW_ + r] = xv + d;
        lsum += d * d;
    }
#pragma unroll
    for (int off = 32; off >= 1; off >>= 1) lsum += __shfl_down(lsum, off, 64);
    __shared__ float wsum[4];
    if ((t & 63) == 0) wsum[t >> 6] = lsum;
    __syncthreads();
    if (t == 0)
        atomicAdd(loss_acc, (double)(wsum[0] + wsum[1] + wsum[2] + wsum[3]));
}

__global__ void finalize_kernel(const double* __restrict__ acc, float* __restrict__ loss_out)
{
    const double s = *acc;
    const float m = (float)(s / (double)((size_t)N_ * C_));
    loss_out[0] = m;
    loss_out[1] = m;
}

extern "C" void kernel_launch(void* const* d_in, const int* in_sizes, int n_in,
                              void* d_out, int out_size, void* d_ws, size_t ws_size,
                              hipStream_t stream)
{
    (void)in_sizes; (void)n_in; (void)out_size; (void)d_ws; (void)ws_size;
    const float* x = (const float*)d_in[0];
    const float* w = (const float*)d_in[1];
    float* out = (float*)d_out;

    float*          w_t    = out + WT_F;
    float*          wn     = out + WN_F;
    unsigned short* whb    = (unsigned short*)(out + WHB_F);
    unsigned short* wlb    = (unsigned short*)(out + WLB_F);
    int*            rlist  = (int*)(out + RLIST_F);
    int*            rcount = (int*)(out + RCNT_F);
    float*          seq    = out + SEQ_OFF;
    double*         loss_acc = (double*)(out + LOSS_OFF);

    transpose_w_kernel<<<256, 256, 0, stream>>>(w, w_t);
    wnorm_kernel<<<4, 256, 0, stream>>>(w, wn);
    wsplit_frag_kernel<<<128, 256, 0, stream>>>(w, whb, wlb);
    hipMemsetAsync((void*)rcount, 0, 4, stream);
    argmin_mfma_kernel<<<512, 256, 0, stream>>>(x, whb, wlb, wn, seq, rlist, rcount);
    rescue_kernel<<<1024, 256, 0, stream>>>(x, w_t, wn, rlist, rcount, seq);
    hipMemsetAsync((char*)d_out + (size_t)LOSS_OFF * 4, 0, 8, stream);
    gather_kernel<<<1024, 256, 0, stream>>>(x, w, seq, out, loss_acc);
    finalize_kernel<<<1, 1, 0, stream>>>(loss_acc, out + LOSS_OFF);
}